// Round 1
// baseline (1642.532 us; speedup 1.0000x reference)
//
#include <hip/hip_runtime.h>
#include <math.h>

#define NN 50000
#define NE 400000
#define DDIM 128
#define NHEAD 4
#define NRAD 50
#define NGRAPH 100
#define TEMB 32
#define DOUT 512
#define CUTF 6.0f
#define PI_F 3.14159265358979323846f

// ---------------- helpers ----------------

__device__ __forceinline__ float gelu_tanh(float v) {
  // jax.nn.gelu default (approximate=True, tanh form)
  float u = 0.7978845608028654f * (v + 0.044715f * v * v * v);
  return 0.5f * v * (1.0f + tanhf(u));
}

__device__ __forceinline__ unsigned f_enc(float f) {
  unsigned u = __float_as_uint(f);
  return u ^ ((unsigned)((int)u >> 31) | 0x80000000u); // order-preserving uint
}
__device__ __forceinline__ float f_dec(unsigned u) {
  unsigned m = (u & 0x80000000u) ? 0x80000000u : 0xFFFFFFFFu;
  return __uint_as_float(u ^ m);
}

__global__ void k_fill_f(float* p, float v, int n) {
  int i = blockIdx.x * blockDim.x + threadIdx.x;
  if (i < n) p[i] = v;
}
__global__ void k_fill_u(unsigned* p, unsigned v, int n) {
  int i = blockIdx.x * blockDim.x + threadIdx.x;
  if (i < n) p[i] = v;
}

// ---------------- init: x = [emb[at], pos] @ W_init + b ----------------

__global__ void k_init(const float* __restrict__ pos, const int* __restrict__ at,
                       const float* __restrict__ emb, const float* __restrict__ W,
                       const float* __restrict__ b, float* __restrict__ x) {
  int idx = blockIdx.x * blockDim.x + threadIdx.x;
  if (idx >= NN * DDIM) return;
  int n = idx >> 7, c = idx & 127;
  const float* er = emb + (size_t)at[n] * TEMB;
  float acc = b[c];
#pragma unroll
  for (int t = 0; t < TEMB; ++t) acc = fmaf(er[t], W[t * DDIM + c], acc);
  acc = fmaf(pos[n * 3 + 0], W[(TEMB + 0) * DDIM + c], acc);
  acc = fmaf(pos[n * 3 + 1], W[(TEMB + 1) * DDIM + c], acc);
  acc = fmaf(pos[n * 3 + 2], W[(TEMB + 2) * DDIM + c], acc);
  x[idx] = acc;
}

// ---------------- per-edge distance ----------------

__global__ void k_dist(const float* __restrict__ pos, const int* __restrict__ ei,
                       float* __restrict__ de) {
  int e = blockIdx.x * blockDim.x + threadIdx.x;
  if (e >= NE) return;
  int s = ei[e], t = ei[NE + e];
  float dx = pos[s * 3 + 0] - pos[t * 3 + 0] + 1e-8f;
  float dy = pos[s * 3 + 1] - pos[t * 3 + 1] + 1e-8f;
  float dz = pos[s * 3 + 2] - pos[t * 3 + 2] + 1e-8f;
  de[e] = sqrtf(dx * dx + dy * dy + dz * dz);
}

// ---------------- generic 128x128 GEMM: out = act(A@W + bias) (+ resid) ----------------
// block 256: 32 rows x 128 cols, 4x4 register tile per thread.
// W staged transposed in LDS with XOR swizzle on k to avoid bank conflicts.

#define GEMM_ROWS 32
template <bool BIAS, bool ACT_GELU, bool RESID>
__global__ __launch_bounds__(256, 2) void k_gemm(
    const float* __restrict__ A, const float* __restrict__ W,
    const float* __restrict__ bias, const float* __restrict__ resid,
    float* __restrict__ out, int nrows) {
  __shared__ float Wl[DDIM * DDIM];        // 64 KB, [c][k^swz]
  __shared__ float Al[GEMM_ROWS * DDIM];   // 16 KB
  const int tid = threadIdx.x;
  const int r0 = blockIdx.x * GEMM_ROWS;

  // stage W transposed + swizzled
  for (int i = tid; i < DDIM * (DDIM / 4); i += 256) {
    int k = i >> 5;
    int c4 = (i & 31) << 2;
    float4 wv = *(const float4*)&W[k * DDIM + c4];
    float vals[4] = {wv.x, wv.y, wv.z, wv.w};
#pragma unroll
    for (int j = 0; j < 4; ++j) {
      int c = c4 + j;
      Wl[c * DDIM + (k ^ (((c >> 2) & 7) << 2))] = vals[j];
    }
  }
  // stage A tile (guard tail rows)
  for (int i = tid; i < GEMM_ROWS * (DDIM / 4); i += 256) {
    int r = i >> 5;
    int k4 = (i & 31) << 2;
    int gr = r0 + r;
    float4 av = (gr < nrows) ? *(const float4*)&A[(size_t)gr * DDIM + k4]
                             : make_float4(0.f, 0.f, 0.f, 0.f);
    *(float4*)&Al[r * DDIM + k4] = av;
  }
  __syncthreads();

  const int cidx = tid & 31;   // 32 col-quads
  const int ridx = tid >> 5;   // 8 row-quads
  const int cbase = cidx << 2;
  const int swz = (cidx & 7) << 2;
  float acc[4][4];
#pragma unroll
  for (int i = 0; i < 4; ++i)
#pragma unroll
    for (int j = 0; j < 4; ++j) acc[i][j] = 0.f;

  for (int k = 0; k < DDIM; k += 4) {
    float4 a[4], w[4];
#pragma unroll
    for (int i = 0; i < 4; ++i) a[i] = *(float4*)&Al[(ridx * 4 + i) * DDIM + k];
#pragma unroll
    for (int j = 0; j < 4; ++j) w[j] = *(float4*)&Wl[(cbase + j) * DDIM + (k ^ swz)];
#pragma unroll
    for (int i = 0; i < 4; ++i)
#pragma unroll
      for (int j = 0; j < 4; ++j) {
        acc[i][j] = fmaf(a[i].x, w[j].x, acc[i][j]);
        acc[i][j] = fmaf(a[i].y, w[j].y, acc[i][j]);
        acc[i][j] = fmaf(a[i].z, w[j].z, acc[i][j]);
        acc[i][j] = fmaf(a[i].w, w[j].w, acc[i][j]);
      }
  }

#pragma unroll
  for (int i = 0; i < 4; ++i) {
    int r = r0 + ridx * 4 + i;
    if (r >= nrows) continue;
#pragma unroll
    for (int j = 0; j < 4; ++j) {
      int c = cbase + j;
      float v = acc[i][j];
      if (BIAS) v += bias[c];
      if (ACT_GELU) v = gelu_tanh(v);
      if (RESID) v += resid[(size_t)r * DDIM + c];
      out[(size_t)r * DDIM + c] = v;
    }
  }
}

// ---------------- edge logits: logit[e,h] = scale * sum_dk q_dst*(k_src + ef) ----------------
// block 256 = 2 edges x 128 dims. ef = rb @ We computed on the fly, skipped when env==0.

__device__ __forceinline__ float rbf_fill(float d, int j) {
  const float step = CUTF / (NRAD - 1);
  const float gamma = (NRAD / CUTF) * (NRAD / CUTF);
  float mu = j * step;
  float dm = d - mu;
  float env = 0.5f * (cosf(PI_F * d / CUTF) + 1.0f);
  return expf(-gamma * dm * dm) * env;
}

__global__ void k_logits(const float* __restrict__ qn, const float* __restrict__ kn,
                         const float* __restrict__ de, const int* __restrict__ ei,
                         const float* __restrict__ We, float* __restrict__ logitp) {
  const int le = threadIdx.x >> 7;
  const int t = threadIdx.x & 127;
  const int e = blockIdx.x * 2 + le;  // NE even, grid exact
  __shared__ float rb[2][NRAD];
  const float d = de[e];
  const bool near = d < CUTF;
  if (near && t < NRAD) rb[le][t] = rbf_fill(d, t);
  __syncthreads();
  const int s = ei[e], dst = ei[NE + e];
  float q = qn[(size_t)dst * DDIM + t];
  float kk = kn[(size_t)s * DDIM + t];
  float ef = 0.f;
  if (near) {
#pragma unroll
    for (int j = 0; j < NRAD; ++j) ef = fmaf(rb[le][j], We[j * DDIM + t], ef);
  }
  float p = q * (kk + ef);
  p += __shfl_xor(p, 16);
  p += __shfl_xor(p, 8);
  p += __shfl_xor(p, 4);
  p += __shfl_xor(p, 2);
  p += __shfl_xor(p, 1);
  if ((t & 31) == 0) logitp[(size_t)e * NHEAD + (t >> 5)] = p * 0.17677669529663687f;
}

// ---------------- segmented softmax (3 passes over edges) ----------------

__global__ void k_segmax(const float* __restrict__ logitp, const int* __restrict__ ei,
                         unsigned* __restrict__ nmax) {
  int idx = blockIdx.x * blockDim.x + threadIdx.x;
  if (idx >= NE * NHEAD) return;
  int e = idx >> 2, h = idx & 3;
  atomicMax(&nmax[(size_t)ei[NE + e] * NHEAD + h], f_enc(logitp[idx]));
}

__global__ void k_expsum(float* __restrict__ logitp, const int* __restrict__ ei,
                         const unsigned* __restrict__ nmax, float* __restrict__ nsum) {
  int idx = blockIdx.x * blockDim.x + threadIdx.x;
  if (idx >= NE * NHEAD) return;
  int e = idx >> 2, h = idx & 3;
  int dst = ei[NE + e];
  float m = f_dec(nmax[(size_t)dst * NHEAD + h]);
  float p = expf(logitp[idx] - m);
  logitp[idx] = p;
  atomicAdd(&nsum[(size_t)dst * NHEAD + h], p);
}

// ---------------- message scatter: msg[dst] += a * (v_src + ef) ----------------

__global__ void k_msg(const float* __restrict__ vn, const float* __restrict__ de,
                      const int* __restrict__ ei, const float* __restrict__ We,
                      const float* __restrict__ logitp, const float* __restrict__ nsum,
                      float* __restrict__ msg) {
  const int le = threadIdx.x >> 7;
  const int t = threadIdx.x & 127;
  const int e = blockIdx.x * 2 + le;
  __shared__ float rb[2][NRAD];
  const float d = de[e];
  const bool near = d < CUTF;
  if (near && t < NRAD) rb[le][t] = rbf_fill(d, t);
  __syncthreads();
  const int s = ei[e], dst = ei[NE + e];
  float ef = 0.f;
  if (near) {
#pragma unroll
    for (int j = 0; j < NRAD; ++j) ef = fmaf(rb[le][j], We[j * DDIM + t], ef);
  }
  int h = t >> 5;
  float a = logitp[(size_t)e * NHEAD + h] / (nsum[(size_t)dst * NHEAD + h] + 1e-9f);
  atomicAdd(&msg[(size_t)dst * DDIM + t], a * (vn[(size_t)s * DDIM + t] + ef));
}

// ---------------- layernorm (per node, 1 wave) ----------------

__global__ void k_ln(const float* __restrict__ x, const float* __restrict__ g,
                     const float* __restrict__ b, float* __restrict__ h) {
  int n = blockIdx.x;
  int t = threadIdx.x;  // 64
  float v0 = x[(size_t)n * DDIM + t];
  float v1 = x[(size_t)n * DDIM + 64 + t];
  float s = v0 + v1;
  float ss = v0 * v0 + v1 * v1;
#pragma unroll
  for (int m = 32; m >= 1; m >>= 1) {
    s += __shfl_xor(s, m);
    ss += __shfl_xor(ss, m);
  }
  float mean = s * (1.0f / DDIM);
  float var = ss * (1.0f / DDIM) - mean * mean;
  float inv = rsqrtf(var + 1e-5f);
  h[(size_t)n * DDIM + t] = (v0 - mean) * inv * g[t] + b[t];
  h[(size_t)n * DDIM + 64 + t] = (v1 - mean) * inv * g[64 + t] + b[64 + t];
}

// ---------------- graph sum (batch is sorted) ----------------

__global__ void k_graphsum(const float* __restrict__ x, const int* __restrict__ batch,
                           float* __restrict__ g) {
  int t = threadIdx.x;  // 128 dims
  int n0 = blockIdx.x * 512;
  int nend = n0 + 512;
  if (nend > NN) nend = NN;
  if (n0 >= NN) return;
  float acc = 0.f;
  int cur = batch[n0];
  for (int n = n0; n < nend; ++n) {
    int bb = batch[n];
    if (bb != cur) {
      atomicAdd(&g[(size_t)cur * DDIM + t], acc);
      acc = 0.f;
      cur = bb;
    }
    acc += x[(size_t)n * DDIM + t];
  }
  atomicAdd(&g[(size_t)cur * DDIM + t], acc);
}

// ---------------- output projection: out = g @ W_out + b_out ----------------

__global__ void k_out(const float* __restrict__ g, const float* __restrict__ W,
                      const float* __restrict__ b, float* __restrict__ out) {
  int idx = blockIdx.x * blockDim.x + threadIdx.x;
  if (idx >= NGRAPH * DOUT) return;
  int r = idx / DOUT, c = idx % DOUT;
  float acc = b[c];
#pragma unroll 8
  for (int k = 0; k < DDIM; ++k) acc = fmaf(g[r * DDIM + k], W[k * DOUT + c], acc);
  out[idx] = acc;
}

// ---------------- launch ----------------

extern "C" void kernel_launch(void* const* d_in, const int* in_sizes, int n_in,
                              void* d_out, int out_size, void* d_ws, size_t ws_size,
                              hipStream_t stream) {
  const float* pos = (const float*)d_in[0];
  const int* at = (const int*)d_in[1];
  const int* ei = (const int*)d_in[2];
  const int* batch = (const int*)d_in[3];
  const float* emb = (const float*)d_in[4];
  const float* W_init = (const float*)d_in[5];
  const float* b_init = (const float*)d_in[6];
  const float* Wq = (const float*)d_in[7];
  const float* Wk = (const float*)d_in[8];
  const float* Wv = (const float*)d_in[9];
  const float* We = (const float*)d_in[10];
  const float* Wo = (const float*)d_in[11];
  const float* Wm1 = (const float*)d_in[12];
  const float* bm1 = (const float*)d_in[13];
  const float* Wm2 = (const float*)d_in[14];
  const float* bm2 = (const float*)d_in[15];
  const float* ln_g = (const float*)d_in[16];
  const float* ln_b = (const float*)d_in[17];
  const float* W_out = (const float*)d_in[18];
  const float* b_out = (const float*)d_in[19];
  float* out = (float*)d_out;

  const size_t ND = (size_t)NN * DDIM;
  float* x = (float*)d_ws;
  float* qn = x + ND;
  float* kn = qn + ND;   // reused as msg / h2
  float* vn = kn + ND;
  float* de = vn + ND;
  float* logitp = de + NE;
  unsigned* nmax = (unsigned*)(logitp + (size_t)NE * NHEAD);
  float* nsum = (float*)(nmax + (size_t)NN * NHEAD);
  float* gb = nsum + (size_t)NN * NHEAD;
  // total ws: 4*ND + NE + 4*NE + 8*NN + NG*D floats ~= 112 MB

  float* msg = kn;  // alias: kn dead after k_logits
  float* hb = qn;   // alias: qn dead after k_logits

  k_init<<<(NN * DDIM + 255) / 256, 256, 0, stream>>>(pos, at, emb, W_init, b_init, x);
  k_dist<<<(NE + 255) / 256, 256, 0, stream>>>(pos, ei, de);

  const int gemm_grid = (NN + GEMM_ROWS - 1) / GEMM_ROWS;
  for (int l = 0; l < 2; ++l) {
    const float* Wq_l = Wq + (size_t)l * DDIM * DDIM;
    const float* Wk_l = Wk + (size_t)l * DDIM * DDIM;
    const float* Wv_l = Wv + (size_t)l * DDIM * DDIM;
    const float* We_l = We + (size_t)l * NRAD * DDIM;
    const float* Wo_l = Wo + (size_t)l * DDIM * DDIM;
    const float* Wm1_l = Wm1 + (size_t)l * DDIM * DDIM;
    const float* Wm2_l = Wm2 + (size_t)l * DDIM * DDIM;

    // q/k/v projections (vn computed first so kn can be overwritten later)
    k_gemm<false, false, false><<<gemm_grid, 256, 0, stream>>>(x, Wq_l, nullptr, nullptr, qn, NN);
    k_gemm<false, false, false><<<gemm_grid, 256, 0, stream>>>(x, Wk_l, nullptr, nullptr, kn, NN);
    k_gemm<false, false, false><<<gemm_grid, 256, 0, stream>>>(x, Wv_l, nullptr, nullptr, vn, NN);

    k_logits<<<NE / 2, 256, 0, stream>>>(qn, kn, de, ei, We_l, logitp);

    k_fill_u<<<(NN * NHEAD + 255) / 256, 256, 0, stream>>>(nmax, 0x007FFFFFu, NN * NHEAD);
    k_fill_f<<<(NN * NHEAD + 255) / 256, 256, 0, stream>>>(nsum, 0.f, NN * NHEAD);
    k_segmax<<<(NE * NHEAD + 255) / 256, 256, 0, stream>>>(logitp, ei, nmax);
    k_expsum<<<(NE * NHEAD + 255) / 256, 256, 0, stream>>>(logitp, ei, nmax, nsum);

    k_fill_f<<<(int)((ND + 255) / 256), 256, 0, stream>>>(msg, 0.f, (int)ND);
    k_msg<<<NE / 2, 256, 0, stream>>>(vn, de, ei, We_l, logitp, nsum, msg);

    // x += msg @ Wo
    k_gemm<false, false, true><<<gemm_grid, 256, 0, stream>>>(msg, Wo_l, nullptr, x, x, NN);
    // pre-norm FC block
    k_ln<<<NN, 64, 0, stream>>>(x, ln_g + (size_t)l * DDIM, ln_b + (size_t)l * DDIM, hb);
    // h2 = gelu(hb @ Wm1 + bm1) -> msg buffer
    k_gemm<true, true, false><<<gemm_grid, 256, 0, stream>>>(hb, Wm1_l, bm1 + (size_t)l * DDIM, nullptr, msg, NN);
    // x += h2 @ Wm2 + bm2
    k_gemm<true, false, true><<<gemm_grid, 256, 0, stream>>>(msg, Wm2_l, bm2 + (size_t)l * DDIM, x, x, NN);
  }

  k_fill_f<<<(NGRAPH * DDIM + 255) / 256, 256, 0, stream>>>(gb, 0.f, NGRAPH * DDIM);
  k_graphsum<<<(NN + 511) / 512, 128, 0, stream>>>(x, batch, gb);
  k_out<<<(NGRAPH * DOUT + 255) / 256, 256, 0, stream>>>(gb, W_out, b_out, out);
}